// Round 9
// baseline (270.553 us; speedup 1.0000x reference)
//
#include <hip/hip_runtime.h>
#include <hip/hip_bf16.h>
#include <cstdint>
#include <cstddef>

#define Hh 8
#define DIN 512
#define CONVD 640
#define DPROJ 1168
#define NTOK 8192
#define DIM 256

typedef __attribute__((ext_vector_type(8))) short short8;
typedef __attribute__((ext_vector_type(4))) float f32x4;

static __device__ __forceinline__ float sigmoidf_(float x) { return 1.f / (1.f + expf(-x)); }
static __device__ __forceinline__ unsigned short f2b(float f) {
  __hip_bfloat16 h = __float2bfloat16(f);
  return *(unsigned short*)&h;
}
static __device__ __forceinline__ float b2f(unsigned short u) {
  union { unsigned int i; float f; } cv; cv.i = ((unsigned int)u) << 16; return cv.f;
}

// ---------------------------------------------------------------------------
// K0: fp32->bf16: x, [Wfx|Wx]->wcat, outw, inw, how; bcat=[bfx|bx] fp32.
__global__ __launch_bounds__(256) void k_cvt(
    const float* __restrict__ x, const float* __restrict__ wfx, const float* __restrict__ wx,
    const float* __restrict__ outw, const float* __restrict__ inw, const float* __restrict__ how,
    const float* __restrict__ bfx, const float* __restrict__ bx,
    unsigned short* __restrict__ xb, unsigned short* __restrict__ wcat,
    unsigned short* __restrict__ outwb, unsigned short* __restrict__ inwb,
    unsigned short* __restrict__ howb, float* __restrict__ bcat) {
  const int e = (blockIdx.x * 256 + threadIdx.x) * 4;
  if (e >= 9641984) {
    const int i = e - 9641984;  // 0..1023
    float4 v;
    if (i < 512) v = *(const float4*)(bfx + i);
    else         v = *(const float4*)(bx + (i - 512));
    *(float4*)(bcat + i) = v;
    return;
  }
  const float* src; unsigned short* dst; int i;
  if (e < 8388608)       { i = e;           src = x;    dst = xb; }
  else if (e < 8519680)  { i = e - 8388608; src = wfx;  dst = wcat; }
  else if (e < 8650752)  { i = e - 8519680; src = wx;   dst = wcat + 131072; }
  else if (e < 8781824)  { i = e - 8650752; src = outw; dst = outwb; }
  else if (e < 9379840)  { i = e - 8781824; src = inw;  dst = inwb; }
  else                   { i = e - 9379840; src = how;  dst = howb; }
  float4 v = *(const float4*)(src + i);
  ushort4 o;
  o.x = f2b(v.x); o.y = f2b(v.y); o.z = f2b(v.z); o.w = f2b(v.w);
  *(ushort4*)(dst + i) = o;
}

// ---------------------------------------------------------------------------
// K1: fused front GEMM. C = xb @ [W_fx|W_x]^T + bias (M=32768, N=1024, K=256).
// y<4: fx tile stored TRANSPOSED to cbT[(b,h,p)][n].
// y>=4: scores+softmax in-block; writes swb[n][g] AND swT[(b,h,g)][n].
__global__ __launch_bounds__(256) void k_front(
    const unsigned short* __restrict__ xb, const unsigned short* __restrict__ wcat,
    const float* __restrict__ bcat, const float* __restrict__ Wslice,
    const float* __restrict__ bslice, const float* __restrict__ temperature,
    unsigned short* __restrict__ cbT, unsigned short* __restrict__ swb,
    unsigned short* __restrict__ swT) {
  __shared__ unsigned short lds[34816];  // region0 [0,17408): As/Bs then Cs; region1: CsT
  unsigned short* As = lds;              // [kb][130][8]
  unsigned short* Bs = lds + 8320;
  const int tid = threadIdx.x;
  const int m0 = blockIdx.x * 128;
  const int n0 = blockIdx.y * 128;
  const int w = tid >> 6, lane = tid & 63;
  const int l15 = lane & 15, kq = lane >> 4;
  const int wm = (w & 1) * 64, wn = (w >> 1) * 64;
  float bs[4];
#pragma unroll
  for (int j = 0; j < 4; ++j) bs[j] = bcat[n0 + wn + j * 16 + l15];
  f32x4 acc[4][4];
#pragma unroll
  for (int i = 0; i < 4; ++i)
#pragma unroll
    for (int j = 0; j < 4; ++j) acc[i][j] = (f32x4){0.f, 0.f, 0.f, 0.f};
  for (int kt = 0; kt < 256; kt += 64) {
#pragma unroll
    for (int i = 0; i < 4; ++i) {
      const int c = tid + 256 * i, m = c >> 3, kb = c & 7;
      *(short8*)&As[(kb * 130 + m) * 8] = *(const short8*)&xb[(size_t)(m0 + m) * 256 + kt + kb * 8];
      *(short8*)&Bs[(kb * 130 + m) * 8] = *(const short8*)&wcat[(size_t)(n0 + m) * 256 + kt + kb * 8];
    }
    __syncthreads();
#pragma unroll
    for (int kw = 0; kw < 2; ++kw) {
      short8 af[4], bfr[4];
#pragma unroll
      for (int i = 0; i < 4; ++i) {
        af[i]  = *(const short8*)&As[((kw * 4 + kq) * 130 + wm + i * 16 + l15) * 8];
        bfr[i] = *(const short8*)&Bs[((kw * 4 + kq) * 130 + wn + i * 16 + l15) * 8];
      }
#pragma unroll
      for (int i = 0; i < 4; ++i)
#pragma unroll
        for (int j = 0; j < 4; ++j)
          acc[i][j] = __builtin_amdgcn_mfma_f32_16x16x32_bf16(af[i], bfr[j], acc[i][j], 0, 0, 0);
    }
    __syncthreads();
  }
  const int bidx = m0 >> 13, nb = m0 & (NTOK - 1);
  if (blockIdx.y < 4) {
    // fx path: write TRANSPOSED CsT[pcol 128][n 128] (pitch 136) from registers
    unsigned short* CsT = lds;
#pragma unroll
    for (int i = 0; i < 4; ++i)
#pragma unroll
      for (int j = 0; j < 4; ++j)
#pragma unroll
        for (int r = 0; r < 4; ++r) {
          const int n = wm + i * 16 + kq * 4 + r;     // local token
          const int pc = wn + j * 16 + l15;           // local p-col (2 heads)
          CsT[pc * 136 + n] = f2b(acc[i][j][r] + bs[j]);
        }
    __syncthreads();
    const int h0fx = blockIdx.y * 2;
#pragma unroll
    for (int it = 0; it < 8; ++it) {
      const int c = tid + 256 * it;
      const int pr = c >> 4, seg = c & 15;            // 128 p-rows x 16 n-segs
      const int row = (bidx * 8 + h0fx + (pr >> 6)) * 64 + (pr & 63);
      *(short8*)&cbT[(size_t)row * NTOK + nb + seg * 8] = *(const short8*)&CsT[pr * 136 + seg * 8];
    }
    return;
  }
  // ---- sw path: epilogue to Cs normal, then fused scores + softmax (2 heads) ----
  unsigned short* Cs = lds;          // [n 128][col 128] pitch 136
  unsigned short* CsT2 = lds + 17408;  // [g 128][n 128] pitch 136
#pragma unroll
  for (int i = 0; i < 4; ++i)
#pragma unroll
    for (int j = 0; j < 4; ++j)
#pragma unroll
      for (int r = 0; r < 4; ++r) {
        const int m = wm + i * 16 + kq * 4 + r;
        const int n = wn + j * 16 + l15;
        Cs[m * 136 + n] = f2b(acc[i][j][r] + bs[j]);
      }
  __syncthreads();
  const int h0 = (n0 - 512) >> 6;
  short8 sbfr[2][4];
#pragma unroll
  for (int kt = 0; kt < 2; ++kt)
#pragma unroll
    for (int j = 0; j < 4; ++j) {
      const float* wp = Wslice + (j * 16 + l15) * 64 + kt * 32 + kq * 8;
      short8 t;
#pragma unroll
      for (int u = 0; u < 8; ++u) t[u] = (short)f2b(wp[u]);
      sbfr[kt][j] = t;
    }
  float sbs[4];
#pragma unroll
  for (int j = 0; j < 4; ++j) sbs[j] = bslice[j * 16 + l15];
  f32x4 sacc[2][2][4];
#pragma unroll
  for (int hl = 0; hl < 2; ++hl)
#pragma unroll
    for (int i = 0; i < 2; ++i)
#pragma unroll
      for (int j = 0; j < 4; ++j) sacc[hl][i][j] = (f32x4){0.f, 0.f, 0.f, 0.f};
#pragma unroll
  for (int hl = 0; hl < 2; ++hl)
#pragma unroll
    for (int kt = 0; kt < 2; ++kt) {
      short8 af[2];
#pragma unroll
      for (int i = 0; i < 2; ++i)
        af[i] = *(const short8*)&Cs[(w * 32 + i * 16 + l15) * 136 + hl * 64 + kt * 32 + kq * 8];
#pragma unroll
      for (int i = 0; i < 2; ++i)
#pragma unroll
        for (int j = 0; j < 4; ++j)
          sacc[hl][i][j] = __builtin_amdgcn_mfma_f32_16x16x32_bf16(af[i], sbfr[kt][j], sacc[hl][i][j], 0, 0, 0);
    }
  __syncthreads();  // Cs reads done; reuse for softmax output
#pragma unroll
  for (int hl = 0; hl < 2; ++hl) {
    const float invt = 1.f / fmaxf(temperature[h0 + hl], 1e-6f);
#pragma unroll
    for (int i = 0; i < 2; ++i)
#pragma unroll
      for (int r = 0; r < 4; ++r) {
        float v[4];
        float m = -1e30f;
#pragma unroll
        for (int j = 0; j < 4; ++j) { v[j] = (sacc[hl][i][j][r] + sbs[j]) * invt; m = fmaxf(m, v[j]); }
#pragma unroll
        for (int off = 8; off; off >>= 1) m = fmaxf(m, __shfl_xor(m, off));
        float s = 0.f;
#pragma unroll
        for (int j = 0; j < 4; ++j) { v[j] = expf(v[j] - m); s += v[j]; }
#pragma unroll
        for (int off = 8; off; off >>= 1) s += __shfl_xor(s, off);
        const float inv = 1.f / s;
        const int row = w * 32 + i * 16 + kq * 4 + r;
#pragma unroll
        for (int j = 0; j < 4; ++j) {
          const unsigned short sv = f2b(v[j] * inv);
          Cs[row * 136 + hl * 64 + j * 16 + l15] = sv;
          CsT2[(hl * 64 + j * 16 + l15) * 136 + row] = sv;
        }
      }
  }
  __syncthreads();
#pragma unroll
  for (int it = 0; it < 8; ++it) {
    const int c = tid + 256 * it;          // 2048 = 2 heads x 128 rows x 8 segs
    const int head = c >> 10, row = (c >> 3) & 127, seg = c & 7;
    *(short8*)&swb[((size_t)(bidx * 8 + h0 + head) * NTOK + nb + row) * 64 + seg * 8] =
        *(const short8*)&Cs[row * 136 + head * 64 + seg * 8];
  }
#pragma unroll
  for (int it = 0; it < 8; ++it) {
    const int c = tid + 256 * it;          // 2048 = 128 g-rows x 16 n-segs
    const int gl = c >> 4, seg = c & 15;
    const int grow = (bidx * 8 + h0 + (gl >> 6)) * 64 + (gl & 63);
    *(short8*)&swT[(size_t)grow * NTOK + nb + seg * 8] = *(const short8*)&CsT2[gl * 136 + seg * 8];
  }
}

// ---------------------------------------------------------------------------
// K3: st_raw[bh][g][p] += sum_n swT[g][n]*fxT[p][n]; snorm += row-sums.
// Direct global MFMA fragments, no LDS. grid (16 nsplit, 32 bh).
__global__ __launch_bounds__(256) void k_st(
    const unsigned short* __restrict__ swT, const unsigned short* __restrict__ fxT,
    float* __restrict__ st_raw, float* __restrict__ snorm) {
  const int tid = threadIdx.x;
  const int bh = blockIdx.y;
  const int nbase = blockIdx.x * 512;
  const int w = tid >> 6, lane = tid & 63;
  const int l15 = lane & 15, kq = lane >> 4;
  f32x4 acc[4];
#pragma unroll
  for (int i = 0; i < 4; ++i) acc[i] = (f32x4){0.f, 0.f, 0.f, 0.f};
#pragma unroll
  for (int kc = 0; kc < 16; ++kc) {
    const int noff = nbase + kc * 32 + kq * 8;
    const short8 bfr = *(const short8*)&fxT[((size_t)bh * 64 + w * 16 + l15) * NTOK + noff];
#pragma unroll
    for (int mi = 0; mi < 4; ++mi) {
      const short8 af = *(const short8*)&swT[((size_t)bh * 64 + mi * 16 + l15) * NTOK + noff];
      acc[mi] = __builtin_amdgcn_mfma_f32_16x16x32_bf16(af, bfr, acc[mi], 0, 0, 0);
    }
  }
  float* stp = st_raw + (size_t)bh * 4096;
#pragma unroll
  for (int mi = 0; mi < 4; ++mi)
#pragma unroll
    for (int r = 0; r < 4; ++r)
      atomicAdd(&stp[(mi * 16 + kq * 4 + r) * 64 + w * 16 + l15], acc[mi][r]);
  // snorm: thread handles g = tid&63, quarter q = tid>>6 (128 n each)
  {
    const int g = tid & 63, q = tid >> 6;
    const unsigned short* sp = &swT[((size_t)bh * 64 + g) * NTOK + nbase + q * 128];
    float sn = 0.f;
#pragma unroll
    for (int u = 0; u < 16; ++u) {
      short8 sv = *(const short8*)&sp[u * 8];
#pragma unroll
      for (int e = 0; e < 8; ++e) sn += b2f((unsigned short)sv[e]);
    }
    atomicAdd(&snorm[bh * 64 + g], sn);
  }
}

// ---------------------------------------------------------------------------
// K3b: st2b[b*64+g][h*64+p] = st_raw / (snorm + 1e-5)  (bf16)
__global__ __launch_bounds__(256) void k_stnorm(
    const float* __restrict__ st_raw, const float* __restrict__ snorm,
    unsigned short* __restrict__ st2b) {
  const int idx = blockIdx.x * 256 + threadIdx.x;
  const int p = idx & 63, g = (idx >> 6) & 63, h = (idx >> 12) & 7, b = idx >> 15;
  const float v = st_raw[idx] / (snorm[(b * Hh + h) * 64 + g] + 1e-5f);
  st2b[(size_t)(b * 64 + g) * DIN + h * 64 + p] = f2b(v);
}

// ---------------------------------------------------------------------------
// K4: zx = st2b (256x512) @ inwb^T (1168x512). MFMA, no LDS.
__global__ __launch_bounds__(256) void k_inproj(
    const unsigned short* __restrict__ st2b, const unsigned short* __restrict__ inwb,
    float* __restrict__ zx) {
  const int tid = threadIdx.x;
  const int m0 = blockIdx.x * 64;
  const int n0 = blockIdx.y * 64;
  const int w = tid >> 6, lane = tid & 63;
  const int l15 = lane & 15, kq = lane >> 4;
  f32x4 acc[4];
#pragma unroll
  for (int j = 0; j < 4; ++j) acc[j] = (f32x4){0.f, 0.f, 0.f, 0.f};
  const int arow = m0 + w * 16 + l15;
#pragma unroll
  for (int kc = 0; kc < 16; ++kc) {
    const short8 af = *(const short8*)&st2b[(size_t)arow * DIN + kc * 32 + kq * 8];
#pragma unroll
    for (int j = 0; j < 4; ++j) {
      int brow = n0 + j * 16 + l15;
      if (brow >= DPROJ) brow = 0;
      const short8 bfr = *(const short8*)&inwb[(size_t)brow * DIN + kc * 32 + kq * 8];
      acc[j] = __builtin_amdgcn_mfma_f32_16x16x32_bf16(af, bfr, acc[j], 0, 0, 0);
    }
  }
#pragma unroll
  for (int j = 0; j < 4; ++j)
#pragma unroll
    for (int r = 0; r < 4; ++r) {
      const int m = m0 + w * 16 + kq * 4 + r;
      const int c = n0 + j * 16 + l15;
      if (c < DPROJ) zx[(size_t)m * DPROJ + c] = acc[j][r];
    }
}

// ---------------------------------------------------------------------------
// K4b: conv(k=3)+silu; dt2 / ldA2 (LOG decay).
__global__ __launch_bounds__(256) void k_prep(
    const float* __restrict__ zx, const float* __restrict__ convw, const float* __restrict__ convb,
    const float* __restrict__ dtbias, const float* __restrict__ Alog,
    float* __restrict__ xbc, float* __restrict__ dt2, float* __restrict__ ldA2) {
  const int idx = blockIdx.x * 256 + threadIdx.x;
  const int NCONV = 4 * 64 * CONVD;
  if (idx < NCONV) {
    const int c = idx % CONVD;
    const int l = (idx / CONVD) & 63;
    const int b = idx / (CONVD * 64);
    float acc = convb[c];
#pragma unroll
    for (int k = 0; k < 3; ++k) {
      const int ls = l - 2 + k;
      if (ls >= 0) acc += zx[(size_t)(b * 64 + ls) * DPROJ + DIN + c] * convw[c * 3 + k];
    }
    xbc[idx] = acc * sigmoidf_(acc);
  } else if (idx < NCONV + 8 * 64 * 8) {
    const int j = idx - NCONV;
    const int h = j & 7, l = (j >> 3) & 63, bb = j >> 9;
    float raw;
    if (bb < 4) raw = zx[(size_t)(bb * 64 + l) * DPROJ + 1152 + h];
    else        raw = zx[(size_t)((bb - 4) * 64 + (63 - l)) * DPROJ + 1160 + h];
    const float d = raw + dtbias[h];
    const float sp = (d > 20.f) ? d : log1pf(expf(d));
    dt2[j] = sp;
    ldA2[j] = sp * -expf(Alog[h]);
  }
}

// ---------------------------------------------------------------------------
// K5: SSM via decay-matrix MFMA form. One block per (bb,h).
__global__ __launch_bounds__(256) void k_ssm(
    const float* __restrict__ xbc, const float* __restrict__ dt2, const float* __restrict__ ldA2,
    float* __restrict__ ys) {
  __shared__ unsigned short s_C[64][72];
  __shared__ unsigned short s_Bm[64][72];
  __shared__ unsigned short s_X[64][72];
  __shared__ unsigned short s_G[64][72];
  __shared__ float s_L[64];
  __shared__ float s_dt[64];
  const int blk = blockIdx.x;
  const int h = blk & 7, bb = blk >> 3;
  const int b = (bb < 4) ? bb : bb - 4;
  const bool rev = bb >= 4;
  const int tid = threadIdx.x;
  const int w = tid >> 6, lane = tid & 63;
  const int l15 = lane & 15, kq = lane >> 4;
  {
    const int l = tid >> 2, part = tid & 3;
    const int t = rev ? 63 - l : l;
    const float* src = xbc + (size_t)(b * 64 + l) * CONVD + DIN + part * 32;
#pragma unroll
    for (int u = 0; u < 32; u += 4) {
      float4 v = *(const float4*)(src + u);
      const int c = part * 32 + u;
      unsigned short* dst = (c < 64) ? &s_Bm[t][c] : &s_C[t][c - 64];
      dst[0] = f2b(v.x); dst[1] = f2b(v.y); dst[2] = f2b(v.z); dst[3] = f2b(v.w);
    }
    const float* xs = xbc + (size_t)(b * 64 + l) * CONVD + h * 64 + part * 16;
#pragma unroll
    for (int u = 0; u < 16; u += 4) {
      float4 v = *(const float4*)(xs + u);
      const int p = part * 16 + u;
      s_X[p + 0][t] = f2b(v.x); s_X[p + 1][t] = f2b(v.y);
      s_X[p + 2][t] = f2b(v.z); s_X[p + 3][t] = f2b(v.w);
    }
  }
  if (w == 0) {
    const float dtv = dt2[(bb * 64 + lane) * 8 + h];
    float ld = ldA2[(bb * 64 + lane) * 8 + h];
#pragma unroll
    for (int off = 1; off < 64; off <<= 1) {
      const float o = __shfl_up(ld, off);
      if (lane >= off) ld += o;
    }
    s_L[lane] = ld;
    s_dt[lane] = dtv;
  }
  __syncthreads();
  f32x4 accS[4];
#pragma unroll
  for (int i = 0; i < 4; ++i) accS[i] = (f32x4){0.f, 0.f, 0.f, 0.f};
#pragma unroll
  for (int kw = 0; kw < 2; ++kw) {
    const short8 bfr = *(const short8*)&s_Bm[w * 16 + l15][kw * 32 + kq * 8];
#pragma unroll
    for (int i = 0; i < 4; ++i) {
      const short8 af = *(const short8*)&s_C[i * 16 + l15][kw * 32 + kq * 8];
      accS[i] = __builtin_amdgcn_mfma_f32_16x16x32_bf16(af, bfr, accS[i], 0, 0, 0);
    }
  }
  const int s_idx = w * 16 + l15;
  const float Ls = s_L[s_idx];
  const float dts = s_dt[s_idx];
#pragma unroll
  for (int i = 0; i < 4; ++i)
#pragma unroll
    for (int r = 0; r < 4; ++r) {
      const int t = i * 16 + kq * 4 + r;
      const float g = (s_idx <= t) ? accS[i][r] * expf(s_L[t] - Ls) * dts : 0.f;
      s_G[t][s_idx] = f2b(g);
    }
  __syncthreads();
  f32x4 accY[4];
#pragma unroll
  for (int i = 0; i < 4; ++i) accY[i] = (f32x4){0.f, 0.f, 0.f, 0.f};
#pragma unroll
  for (int kw = 0; kw < 2; ++kw) {
    const short8 bfr = *(const short8*)&s_X[w * 16 + l15][kw * 32 + kq * 8];
#pragma unroll
    for (int i = 0; i < 4; ++i) {
      const short8 af = *(const short8*)&s_G[i * 16 + l15][kw * 32 + kq * 8];
      accY[i] = __builtin_amdgcn_mfma_f32_16x16x32_bf16(af, bfr, accY[i], 0, 0, 0);
    }
  }
#pragma unroll
  for (int i = 0; i < 4; ++i)
#pragma unroll
    for (int r = 0; r < 4; ++r) {
      const int t = i * 16 + kq * 4 + r;
      ys[(((size_t)(bb * 64 + t) * 8 + h) << 6) + w * 16 + l15] = accY[i][r];
    }
}

// ---------------------------------------------------------------------------
// K6a: combine + gate + RMS norm; emits bf16 ygb.
__global__ __launch_bounds__(256) void k_gate(
    const float* __restrict__ ys, const float* __restrict__ xbc, const float* __restrict__ zx,
    const float* __restrict__ fcdw, const float* __restrict__ Dp,
    const float* __restrict__ normw, unsigned short* __restrict__ ygb) {
  __shared__ float red[256][9];
  __shared__ float s_xfc[8];
  const int bl = blockIdx.x;
  const int b = bl >> 6, l = bl & 63;
  const int tid = threadIdx.x;
  const float xog0 = xbc[(size_t)bl * CONVD + tid];
  const float xog1 = xbc[(size_t)bl * CONVD + 256 + tid];
#pragma unroll
  for (int h = 0; h < 8; ++h)
    red[tid][h] = xog0 * fcdw[h * DIN + tid] + xog1 * fcdw[h * DIN + 256 + tid];
  __syncthreads();
  for (int s = 128; s > 0; s >>= 1) {
    if (tid < s) {
#pragma unroll
      for (int h = 0; h < 8; ++h) red[tid][h] += red[tid + s][h];
    }
    __syncthreads();
  }
  if (tid < 8) s_xfc[tid] = red[0][tid] + Dp[tid];
  __syncthreads();
  float ygv[2];
  float sumsq = 0.f;
#pragma unroll
  for (int ci = 0; ci < 2; ++ci) {
    const int c = tid + ci * 256;
    const int h = c >> 6, p = c & 63;
    float yv = 0.f;
    if (l >= 1)  yv += ys[(((size_t)(b * 64 + (l - 1)) * 8 + h) << 6) + p];
    if (l <= 62) yv += ys[(((size_t)((4 + b) * 64 + (62 - l)) * 8 + h) << 6) + p];
    const float xog = (ci == 0) ? xog0 : xog1;
    yv += xog * s_xfc[h];
    const float z = zx[(size_t)bl * DPROJ + c];
    const float g = yv * (z * sigmoidf_(z));
    ygv[ci] = g;
    sumsq += g * g;
  }
  red[tid][0] = sumsq;
  __syncthreads();
  for (int s = 128; s > 0; s >>= 1) {
    if (tid < s) red[tid][0] += red[tid + s][0];
    __syncthreads();
  }
  const float scale = 1.f / sqrtf(red[0][0] / 512.f + 1e-5f);
#pragma unroll
  for (int ci = 0; ci < 2; ++ci) {
    const int c = tid + ci * 256;
    ygb[(size_t)bl * DIN + c] = f2b(ygv[ci] * scale * normw[c]);
  }
}

// ---------------------------------------------------------------------------
// K6b: ot = ygb (256x512) @ howb^T. Writes otT bf16 [(b,h,p)][g]. grid (4,8).
__global__ __launch_bounds__(256) void k_oproj(
    const unsigned short* __restrict__ ygb, const unsigned short* __restrict__ howb,
    unsigned short* __restrict__ otT) {
  __shared__ unsigned short Cs[64][72];
  const int tid = threadIdx.x;
  const int b = blockIdx.x;
  const int h = blockIdx.y;
  const int m0 = b * 64, n0 = h * 64;
  const int w = tid >> 6, lane = tid & 63;
  const int l15 = lane & 15, kq = lane >> 4;
  f32x4 acc[4];
#pragma unroll
  for (int j = 0; j < 4; ++j) acc[j] = (f32x4){0.f, 0.f, 0.f, 0.f};
  const int arow = m0 + w * 16 + l15;
#pragma unroll
  for (int kc = 0; kc < 16; ++kc) {
    const short8 af = *(const short8*)&ygb[(size_t)arow * DIN + kc * 32 + kq * 8];
#pragma unroll
    for (int j = 0; j < 4; ++j) {
      const int brow = n0 + j * 16 + l15;
      const short8 bfr = *(const short8*)&howb[(size_t)brow * DIN + kc * 32 + kq * 8];
      acc[j] = __builtin_amdgcn_mfma_f32_16x16x32_bf16(af, bfr, acc[j], 0, 0, 0);
    }
  }
#pragma unroll
  for (int j = 0; j < 4; ++j)
#pragma unroll
    for (int r = 0; r < 4; ++r) {
      const int g = w * 16 + kq * 4 + r;
      const int p = j * 16 + l15;
      Cs[p][g] = f2b(acc[j][r]);
    }
  __syncthreads();
#pragma unroll
  for (int it = 0; it < 2; ++it) {
    const int c = tid + 256 * it;
    const int p = c >> 3, seg = c & 7;
    *(short8*)&otT[(((size_t)(b * 8 + h) * 64 + p) << 6) + seg * 8] = *(const short8*)&Cs[p][seg * 8];
  }
}

// ---------------------------------------------------------------------------
// K7: fused mix + final. One block = 64 tokens of one b.
__global__ __launch_bounds__(256) void k_mixfinal(
    const unsigned short* __restrict__ swb, const unsigned short* __restrict__ otT,
    const unsigned short* __restrict__ outwb, const float* __restrict__ outb,
    float* __restrict__ out) {
  __shared__ unsigned short lm[33280];  // [64][520] bf16, reused as [64][260] fp32
  const int blk = blockIdx.x;           // 512 = 4 b x 128 chunks
  const int b = blk >> 7;
  const int t0 = (blk & 127) * 64;
  const int tid = threadIdx.x;
  const int w = tid >> 6, lane = tid & 63;
  const int l15 = lane & 15, kq = lane >> 4;
#pragma unroll
  for (int hh = 0; hh < 2; ++hh) {
    const int h = w * 2 + hh;
    const int bh = b * 8 + h;
    f32x4 acc[4][4];
#pragma unroll
    for (int i = 0; i < 4; ++i)
#pragma unroll
      for (int j = 0; j < 4; ++j) acc[i][j] = (f32x4){0.f, 0.f, 0.f, 0.f};
#pragma unroll
    for (int kt = 0; kt < 2; ++kt) {
      short8 af[4], bfr[4];
#pragma unroll
      for (int i = 0; i < 4; ++i) {
        af[i]  = *(const short8*)&swb[((size_t)bh * NTOK + t0 + i * 16 + l15) * 64 + kt * 32 + kq * 8];
        bfr[i] = *(const short8*)&otT[(((size_t)bh * 64 + i * 16 + l15) << 6) + kt * 32 + kq * 8];
      }
#pragma unroll
      for (int i = 0; i < 4; ++i)
#pragma unroll
        for (int j = 0; j < 4; ++j)
          acc[i][j] = __builtin_amdgcn_mfma_f32_16x16x32_bf16(af[i], bfr[j], acc[i][j], 0, 0, 0);
    }
#pragma unroll
    for (int i = 0; i < 4; ++i)
#pragma unroll
      for (int j = 0; j < 4; ++j)
#pragma unroll
        for (int r = 0; r < 4; ++r)
          lm[(i * 16 + kq * 4 + r) * 520 + h * 64 + j * 16 + l15] = f2b(acc[i][j][r]);
  }
  __syncthreads();
  float ob[4];
#pragma unroll
  for (int j = 0; j < 4; ++j) ob[j] = outb[w * 64 + j * 16 + l15];
  f32x4 facc[4][4];
#pragma unroll
  for (int i = 0; i < 4; ++i)
#pragma unroll
    for (int j = 0; j < 4; ++j) facc[i][j] = (f32x4){0.f, 0.f, 0.f, 0.f};
#pragma unroll
  for (int kt = 0; kt < 16; ++kt) {
    short8 af[4], bfr[4];
#pragma unroll
    for (int i = 0; i < 4; ++i) {
      af[i]  = *(const short8*)&lm[(i * 16 + l15) * 520 + kt * 32 + kq * 8];
      bfr[i] = *(const short8*)&outwb[(size_t)(w * 64 + i * 16 + l15) * 512 + kt * 32 + kq * 8];
    }
#pragma unroll
    for (int i = 0; i < 4; ++i)
#pragma unroll
      for (int j = 0; j < 4; ++j)
        facc[i][j] = __builtin_amdgcn_mfma_f32_16x16x32_bf16(af[i], bfr[j], facc[i][j], 0, 0, 0);
  }
  __syncthreads();
  float* lf = (float*)lm;  // [64][260]
#pragma unroll
  for (int i = 0; i < 4; ++i)
#pragma unroll
    for (int j = 0; j < 4; ++j)
#pragma unroll
      for (int r = 0; r < 4; ++r)
        lf[(i * 16 + kq * 4 + r) * 260 + w * 64 + j * 16 + l15] = facc[i][j][r] + ob[j];
  __syncthreads();
#pragma unroll
  for (int it = 0; it < 16; ++it) {
    const int c = tid + 256 * it;
    const int row = c >> 6, seg = c & 63;
    *(float4*)&out[((size_t)(b * NTOK + t0 + row)) * 256 + seg * 4] =
        *(const float4*)&lf[row * 260 + seg * 4];
  }
}

// ---------------------------------------------------------------------------
extern "C" void kernel_launch(void* const* d_in, const int* in_sizes, int n_in,
                              void* d_out, int out_size, void* d_ws, size_t ws_size,
                              hipStream_t stream) {
  const float* x      = (const float*)d_in[0];
  const float* Wfx    = (const float*)d_in[1];
  const float* bfx    = (const float*)d_in[2];
  const float* Wx     = (const float*)d_in[3];
  const float* bx     = (const float*)d_in[4];
  const float* Wslice = (const float*)d_in[5];
  const float* bslice = (const float*)d_in[6];
  const float* temp   = (const float*)d_in[7];
  const float* inw    = (const float*)d_in[8];
  const float* convw  = (const float*)d_in[9];
  const float* convb  = (const float*)d_in[10];
  const float* dtbias = (const float*)d_in[11];
  const float* Alog   = (const float*)d_in[12];
  const float* Dp     = (const float*)d_in[13];
  const float* fcdw   = (const float*)d_in[14];
  const float* normw  = (const float*)d_in[15];
  const float* how    = (const float*)d_in[16];
  const float* outw   = (const float*)d_in[17];
  const float* outb   = (const float*)d_in[18];

  unsigned short* us = (unsigned short*)d_ws;
  unsigned short* cbT    = us;                   // 16,777,216 (fx transposed [(b,h,p)][n])
  unsigned short* swb    = cbT + 16777216;       // 16,777,216 ([bh][n][g])
  unsigned short* swTb   = swb + 16777216;       // 16,777,216 ([(b,h,g)][n])
  unsigned short* xbfb   = swTb + 16777216;      //  8,388,608
  unsigned short* wcatb  = xbfb + 8388608;       //    262,144
  unsigned short* outwbf = wcatb + 262144;       //    131,072
  unsigned short* otTb   = outwbf + 131072;      //    131,072
  unsigned short* inwb   = otTb + 131072;        //    598,016
  unsigned short* howb   = inwb + 598016;        //    262,144
  unsigned short* st2b   = howb + 262144;        //    131,072
  unsigned short* ygbb   = st2b + 131072;        //    131,072
  float* fbase = (float*)(ygbb + 131072);
  float* bcat   = fbase;                          //      1,024
  float* st_raw = bcat + 1024;                    //    131,072
  float* snorm  = st_raw + 131072;                //      2,048
  float* zx     = snorm + 2048;                   //    299,008
  float* xbc    = zx + 299008;                    //    163,840
  float* dt2    = xbc + 163840;                   //      4,096
  float* ldA2   = dt2 + 4096;                     //      4,096
  float* ysb    = ldA2 + 4096;                    //    262,144

  hipMemsetAsync(st_raw, 0, (131072 + 2048) * sizeof(float), stream);

  k_cvt     <<<dim3(9417),    256, 0, stream>>>(x, Wfx, Wx, outw, inw, how, bfx, bx,
                                                xbfb, wcatb, outwbf, inwb, howb, bcat);
  k_front   <<<dim3(256, 8),  256, 0, stream>>>(xbfb, wcatb, bcat, Wslice, bslice, temp,
                                                cbT, swb, swTb);
  k_st      <<<dim3(16, 32),  256, 0, stream>>>(swTb, cbT, st_raw, snorm);
  k_stnorm  <<<dim3(512),     256, 0, stream>>>(st_raw, snorm, st2b);
  k_inproj  <<<dim3(4, 19),   256, 0, stream>>>(st2b, inwb, zx);
  k_prep    <<<dim3(656),     256, 0, stream>>>(zx, convw, convb, dtbias, Alog, xbc, dt2, ldA2);
  k_ssm     <<<dim3(64),      256, 0, stream>>>(xbc, dt2, ldA2, ysb);
  k_gate    <<<dim3(256),     256, 0, stream>>>(ysb, xbc, zx, fcdw, Dp, normw, ygbb);
  k_oproj   <<<dim3(4, 8),    256, 0, stream>>>(ygbb, howb, otTb);
  k_mixfinal<<<dim3(512),     256, 0, stream>>>(swb, otTb, outwbf, outb, (float*)d_out);
}